// Round 7
// baseline (117.684 us; speedup 1.0000x reference)
//
#include <hip/hip_runtime.h>
#include <hip/hip_bf16.h>

// loss = (100/N^2) * [3*s_tt + s_rr + s_dd + s_ii - 2*(s_tr + s_td + s_ti)]
// where s_ab = || n_a^T n_b ||_F^2   (n_x = row-normalized input, N=4096, D=512)
//
// fp8 pipeline, 2 dispatches. nT8 layout is k-blocked:
//   nT8[ ((mod*64 + kb)*512 + c)*64 + dk ],  kb = k/64, dk = k%64  (8 MB)
// K1 writes one contiguous 32 KB run per block; K2 wave-fragment loads are
// fully dense contiguous 1 KB segments.
//
// INVARIANT (violated in a prior failed attempt, now restored): the
// Frobenius reduction is local ONLY over the output (M x N) partition --
// every block must integrate the FULL K=4096. ||G0+G1||^2 != ||G0||^2 +
// ||G1||^2. K is never split.
//
// K1 preprocess: SINGLE-READ fused rownorm + scale(16/||r||) + fp8 cast +
//                transpose; zeroes d_out. 64-row strips, 256 blocks (1/CU),
//                512 threads, register-resident 4x4 blocks. (unchanged)
// K2 gram:       ZERO-LDS, ZERO-BARRIER. TN-GEMMs 512x512 fp8 via MX-scaled
//                mfma_scale_f32_16x16x128_f8f6f4, unit scales (0x7F) =
//                plain fp8 product. 1344 single-wave blocks = 336 jobs x 4
//                output quadrants (32x32, 2x2 frags, full K). Fragments load
//                DIRECTLY from L2 into registers (plain HIP loads ->
//                compiler emits counted vmcnt; no global_load_lds, no
//                s_barrier, no manual waits). Register double-buffer one
//                chunk deep. Pair-grouped bijective XCD swizzle (1344 =
//                8 x 168; a job's 4 quadrants adjacent on one XCD) keeps
//                panels L2-resident. Local Frobenius -> 1 atomic/wave.
//                SELF products symmetric => tiles i<=j only, off-diag x2:
//                4*36 + 3*64 = 336 jobs.
// Frobenius structure => immune to any consistent K/row/col permutation and
// to MFMA operand/C/D layouts (A and B always loaded with identical
// formulas); x16 pre-scale folded into normalization, /16^4 at the end.

typedef __attribute__((ext_vector_type(4))) float floatx4;
typedef __attribute__((ext_vector_type(2))) long long llx2;
typedef __attribute__((ext_vector_type(8))) int intx8;

#define N_ROWS 4096
#define DDIM   512
// 100 / (4096^2 * 16^4)
#define LOSS_SCALE 9.094947017729282e-11f

__device__ __forceinline__ const float* sel_mod(int mod, const float* a,
                                                const float* b, const float* c,
                                                const float* d) {
  return mod == 0 ? a : mod == 1 ? b : mod == 2 ? c : d;
}

// bf16 RNE round-trip (keeps nT8 numerics identical to the bf16 pipeline)
__device__ __forceinline__ float bfr(float x) {
  __hip_bfloat16 h = __float2bfloat16(x);
  unsigned short u = *(unsigned short*)&h;
  return __uint_as_float(((unsigned int)u) << 16);
}

__global__ __launch_bounds__(512) void preprocess_kernel(
    const float* __restrict__ in0, const float* __restrict__ in1,
    const float* __restrict__ in2, const float* __restrict__ in3,
    unsigned char* __restrict__ nT8, float* __restrict__ out) {
  // grid: x = 64 (k-strips of 64 rows = one kb block), y = 4 (mod).
  int mod = blockIdx.y;
  int k0 = blockIdx.x * 64;
  const float* X = sel_mod(mod, in0, in1, in2, in3) + (size_t)k0 * DDIM;

  if (blockIdx.x == 0 && blockIdx.y == 0 && threadIdx.x == 0)
    out[0] = 0.f;  // d_out re-poisoned each call; gram (next dispatch) accums

  __shared__ float rsc[64];
  // fp8-packed transpose tile: [512 cols][16 row-groups + 1 pad] words.
  // stride 17 (odd): pack-writes ~8 banks, out-phase b32 reads ~2-way (free).
  __shared__ unsigned int t8[512 * 17];  // 34.8 KB

  int t = threadIdx.x;
  int a = t >> 5;   // row-group 0..15 -> rows 4a..4a+3
  int bg = t & 31;  // col-group: float4 bg within each 128-col panel

  // single global read: 4 rows x 4 panels of float4 -> 64 VGPRs
  float4 v[4][4];  // [q][p]
#pragma unroll
  for (int q = 0; q < 4; ++q)
#pragma unroll
    for (int p = 0; p < 4; ++p)
      v[q][p] = ((const float4*)(X + (size_t)(4 * a + q) * DDIM + p * 128))[bg];

  // row-norm partials from registers; rows of group a live in one 32-lane
  // half-wave (t = a*32 + bg) -> width-32 shfl reduce
  float ss[4];
#pragma unroll
  for (int q = 0; q < 4; ++q) {
    float acc = 0.f;
#pragma unroll
    for (int p = 0; p < 4; ++p) {
      float4 u = v[q][p];
      acc += u.x * u.x + u.y * u.y + u.z * u.z + u.w * u.w;
    }
    ss[q] = acc;
  }
#pragma unroll
  for (int off = 16; off > 0; off >>= 1)
#pragma unroll
    for (int q = 0; q < 4; ++q) ss[q] += __shfl_down(ss[q], off, 32);
  if (bg == 0) {
#pragma unroll
    for (int q = 0; q < 4; ++q)
      rsc[4 * a + q] = 16.0f / fmaxf(sqrtf(ss[q]), 1e-12f);  // x16 folded
  }
  __syncthreads();

  float sc[4];
#pragma unroll
  for (int q = 0; q < 4; ++q) sc[q] = rsc[4 * a + q];

  // scale -> bf16 round -> fp8 pack (4 k-rows per word), straight from regs
#pragma unroll
  for (int p = 0; p < 4; ++p)
#pragma unroll
    for (int j = 0; j < 4; ++j) {
      float f0 = bfr(((const float*)&v[0][p])[j] * sc[0]);
      float f1 = bfr(((const float*)&v[1][p])[j] * sc[1]);
      float f2 = bfr(((const float*)&v[2][p])[j] * sc[2]);
      float f3 = bfr(((const float*)&v[3][p])[j] * sc[3]);
      unsigned int pk = __builtin_amdgcn_cvt_pk_fp8_f32(f0, f1, 0, 0);
      pk = __builtin_amdgcn_cvt_pk_fp8_f32(f2, f3, pk, 1);  // k-order bytes
      t8[(p * 128 + bg * 4 + j) * 17 + a] = pk;
    }
  __syncthreads();

  // output: one contiguous 32 KB region per block (k-blocked layout):
  // flat byte off = c*64 + g*16 = idx*16
  size_t rbase = (size_t)(mod * 64 + blockIdx.x) * 32768;
#pragma unroll
  for (int it = 0; it < 4; ++it) {
    int idx = it * 512 + t;
    int col = idx >> 2;  // 0..511
    int g = idx & 3;     // 16-byte k-group within the 64-row strip
    uint4 o;
    o.x = t8[col * 17 + g * 4 + 0];
    o.y = t8[col * 17 + g * 4 + 1];
    o.z = t8[col * 17 + g * 4 + 2];
    o.w = t8[col * 17 + g * 4 + 3];
    *(uint4*)(nT8 + rbase + (size_t)idx * 16) = o;
  }
}

// 32 B fragment load (two aligned 16 B loads; compiler handles vmcnt)
__device__ __forceinline__ intx8 ldfrag(const unsigned char* __restrict__ p) {
  intx8 r;
  *(llx2*)&r = *(const llx2*)p;
  *((llx2*)&r + 1) = *(const llx2*)(p + 16);
  return r;
}

__global__ __launch_bounds__(64) void gram_frob_kernel(
    const unsigned char* __restrict__ nT8, float* __restrict__ out) {
  // 1344 single-wave blocks = 336 jobs x 4 quadrants (32x32), FULL K each.
  // Bijective XCD swizzle: 1344 = 8 x 168; u consecutive within an XCD =>
  // a job's 4 quadrants and ~42 group-major jobs per XCD.
  int bx = blockIdx.x;
  int u = (bx & 7) * 168 + (bx >> 3);
  int job = u >> 2;
  int quad = u & 3;  // (mh, nh) quadrant of the 64x64 tile
  int mh = quad >> 1;
  int nh = quad & 1;

  // decode job -> (ti, tj, idx-within-group); group-major over unordered
  // strip pairs {ti,tj}: diag groups 7 jobs, off-diag groups 10 jobs.
  int rem = job, ti = 7, tj = 7;
  for (int i = 0; i < 8; ++i) {
    int rowlen = 7 + 10 * (7 - i);
    if (rem < rowlen) {
      if (rem < 7) {
        ti = i; tj = i;
      } else {
        int r2 = rem - 7;
        ti = i; tj = i + 1 + r2 / 10;
        rem = r2 % 10;
      }
      break;
    }
    rem -= rowlen;
  }

  int pa_, pb_, a0, b0;
  float wgt;
  if (ti == tj) {
    if (rem < 4) { pa_ = pb_ = rem; wgt = (rem == 3) ? 3.f : 1.f; }
    else         { pa_ = 3; pb_ = rem - 4; wgt = -2.f; }
    a0 = ti * 64; b0 = ti * 64;
  } else {
    if (rem < 4) {
      pa_ = pb_ = rem; wgt = (rem == 3) ? 6.f : 2.f;  // off-diag self x2
      a0 = ti * 64; b0 = tj * 64;
    } else {
      int k = rem - 4;
      pa_ = 3; pb_ = k >> 1; wgt = -2.f;
      if (k & 1) { a0 = tj * 64; b0 = ti * 64; }
      else       { a0 = ti * 64; b0 = tj * 64; }
    }
  }

  int lane = threadIdx.x;  // one wave per block
  int lm = lane & 15;      // column-within-fragment
  int lq = lane >> 4;      // 32 B k-window: k = lq*32 + b

  // fragment base for chunk 0:
  //   (((lq>>1) * 512) + c) * 64 + (lq&1)*32,  c = cb + lm
  size_t lkb = ((size_t)(lq >> 1) * 512 + lm) * 64 + (size_t)(lq & 1) * 32;
  const unsigned char* pA0 =
      nT8 + (size_t)pa_ * 2097152 + lkb + (size_t)(a0 + 32 * mh) * 64;
  const unsigned char* pA1 = pA0 + 16 * 64;
  const unsigned char* pB0 =
      nT8 + (size_t)pb_ * 2097152 + lkb + (size_t)(b0 + 32 * nh) * 64;
  const unsigned char* pB1 = pB0 + 16 * 64;
#define CHUNK_STRIDE 65536  // 2 kb-blocks * 512 cols * 64 B (K advances 128)

  floatx4 zero = {0.f, 0.f, 0.f, 0.f};
  floatx4 acc[2][2];
  acc[0][0] = zero; acc[0][1] = zero; acc[1][0] = zero; acc[1][1] = zero;

#define MFMA4(AR, BR)                                                        \
  do {                                                                       \
    __builtin_amdgcn_s_setprio(1);                                           \
    acc[0][0] = __builtin_amdgcn_mfma_scale_f32_16x16x128_f8f6f4(            \
        AR[0], BR[0], acc[0][0], 0, 0, 0, 0x7F, 0, 0x7F);                    \
    acc[0][1] = __builtin_amdgcn_mfma_scale_f32_16x16x128_f8f6f4(            \
        AR[0], BR[1], acc[0][1], 0, 0, 0, 0x7F, 0, 0x7F);                    \
    acc[1][0] = __builtin_amdgcn_mfma_scale_f32_16x16x128_f8f6f4(            \
        AR[1], BR[0], acc[1][0], 0, 0, 0, 0x7F, 0, 0x7F);                    \
    acc[1][1] = __builtin_amdgcn_mfma_scale_f32_16x16x128_f8f6f4(            \
        AR[1], BR[1], acc[1][1], 0, 0, 0, 0x7F, 0, 0x7F);                    \
    __builtin_amdgcn_s_setprio(0);                                           \
  } while (0)

  // 32 chunks of K=128 (FULL K), register double-buffer (even chunks in
  // *e, odd in *o). Loads are plain global loads: compiler emits counted
  // vmcnt so the prefetch overlaps the MFMAs; no LDS, no barriers anywhere.
  intx8 ae[2], be[2], ao[2], bo[2];
  ae[0] = ldfrag(pA0); ae[1] = ldfrag(pA1);
  be[0] = ldfrag(pB0); be[1] = ldfrag(pB1);
  for (int ch = 0; ch < 30; ch += 2) {
    pA0 += CHUNK_STRIDE; pA1 += CHUNK_STRIDE;
    pB0 += CHUNK_STRIDE; pB1 += CHUNK_STRIDE;
    ao[0] = ldfrag(pA0); ao[1] = ldfrag(pA1);
    bo[0] = ldfrag(pB0); bo[1] = ldfrag(pB1);
    MFMA4(ae, be);  // chunk ch
    pA0 += CHUNK_STRIDE; pA1 += CHUNK_STRIDE;
    pB0 += CHUNK_STRIDE; pB1 += CHUNK_STRIDE;
    ae[0] = ldfrag(pA0); ae[1] = ldfrag(pA1);
    be[0] = ldfrag(pB0); be[1] = ldfrag(pB1);
    MFMA4(ao, bo);  // chunk ch+1
  }
  pA0 += CHUNK_STRIDE; pA1 += CHUNK_STRIDE;
  pB0 += CHUNK_STRIDE; pB1 += CHUNK_STRIDE;
  ao[0] = ldfrag(pA0); ao[1] = ldfrag(pA1);
  bo[0] = ldfrag(pB0); bo[1] = ldfrag(pB1);
  MFMA4(ae, be);  // chunk 30
  MFMA4(ao, bo);  // chunk 31

  // Local Frobenius: C/D layout is a bijection and the 4 quadrants partition
  // the 64x64 tile -> sum of squares is exact.
  float s = 0.f;
#pragma unroll
  for (int mi = 0; mi < 2; ++mi)
#pragma unroll
    for (int ni = 0; ni < 2; ++ni)
#pragma unroll
      for (int r = 0; r < 4; ++r) {
        float v = acc[mi][ni][r];
        s += v * v;
      }
#pragma unroll
  for (int off = 32; off > 0; off >>= 1) s += __shfl_down(s, off, 64);
  if (lane == 0)
    atomicAdd(out, wgt * LOSS_SCALE * s);  // 1344 atomics total
}

extern "C" void kernel_launch(void* const* d_in, const int* in_sizes, int n_in,
                              void* d_out, int out_size, void* d_ws, size_t ws_size,
                              hipStream_t stream) {
  const float* in_rgb   = (const float*)d_in[0];
  const float* in_depth = (const float*)d_in[1];
  const float* in_ir    = (const float*)d_in[2];
  const float* in_t     = (const float*)d_in[3];

  unsigned char* nT8 = (unsigned char*)d_ws;  // 8 MB fp8, k-blocked layout

  preprocess_kernel<<<dim3(64, 4), 512, 0, stream>>>(
      in_rgb, in_depth, in_ir, in_t, nT8, (float*)d_out);
  gram_frob_kernel<<<dim3(1344), 64, 0, stream>>>(nT8, (float*)d_out);
}

// Round 8
// 103.910 us; speedup vs baseline: 1.1326x; 1.1326x over previous
//
#include <hip/hip_runtime.h>
#include <hip/hip_bf16.h>

// loss = (100/N^2) * [3*s_tt + s_rr + s_dd + s_ii - 2*(s_tr + s_td + s_ti)]
// where s_ab = || n_a^T n_b ||_F^2   (n_x = row-normalized input, N=4096, D=512)
//
// fp8 pipeline, 2 dispatches. nT8 layout is k-blocked:
//   nT8[ ((mod*64 + kb)*512 + c)*64 + dk ],  kb = k/64, dk = k%64  (8 MB)
//
// INVARIANT: Frobenius is local only over the OUTPUT (M x N) partition;
// every block integrates the FULL K=4096. K is never split.
//
// K1 preprocess: SINGLE-READ fused rownorm + scale(16/||r||) + fp8 cast +
//                transpose; zeroes d_out. 64-row strips, 256 blocks (1/CU),
//                512 threads, register-resident 4x4 blocks. (unchanged)
// K2 gram:       TN-GEMMs 512x512 fp8 via MX-scaled
//                mfma_scale_f32_16x16x128_f8f6f4, unit scales (0x7F) =
//                plain fp8 product. 336 blocks x 4 WAVES sharing one staged
//                chunk (TLP fix: 80 KB LDS -> 2 blocks/CU = 8 waves/CU =
//                2/SIMD, double R5). Each wave: stages a quarter-chunk
//                (4 global_load_lds) and computes a 32x32 quadrant (2x2
//                frags, 8 asm ds_read_b128, 4 MFMA per chunk). 5-buffer LDS,
//                4-deep prefetch, per-wave counted vmcnt(12/8/4/0) + raw
//                s_barrier (no drain); opaque asm ds_reads keep the
//                compiler's waitcnt pass out of the pipeline. Pair-grouped
//                bijective XCD swizzle keeps panels L2-resident. Block
//                Frobenius reduce -> 336 atomics.
// Frobenius structure => immune to any consistent K/row/col permutation and
// to MFMA operand/C/D layouts (A and B always loaded with identical
// formulas); x16 pre-scale folded into normalization, /16^4 at the end.

typedef __attribute__((ext_vector_type(4))) float floatx4;
typedef __attribute__((ext_vector_type(2))) long long llx2;
typedef __attribute__((ext_vector_type(8))) int intx8;

typedef __attribute__((address_space(3))) unsigned char* lds_u8p;
typedef const __attribute__((address_space(3))) unsigned char* lds_cu8p;

#define N_ROWS 4096
#define DDIM   512
// 100 / (4096^2 * 16^4)
#define LOSS_SCALE 9.094947017729282e-11f

__device__ __forceinline__ const float* sel_mod(int mod, const float* a,
                                                const float* b, const float* c,
                                                const float* d) {
  return mod == 0 ? a : mod == 1 ? b : mod == 2 ? c : d;
}

// bf16 RNE round-trip (keeps nT8 numerics identical to the bf16 pipeline)
__device__ __forceinline__ float bfr(float x) {
  __hip_bfloat16 h = __float2bfloat16(x);
  unsigned short u = *(unsigned short*)&h;
  return __uint_as_float(((unsigned int)u) << 16);
}

// Opaque LDS read: compiler's waitcnt pass sees a register-only asm and
// inserts no vmcnt/lgkmcnt around it; WE wait with lgkmcnt(0) before use.
__device__ __forceinline__ llx2 ldsr16(lds_cu8p p) {
  llx2 r;
  asm volatile("ds_read_b128 %0, %1" : "=v"(r) : "v"(p));
  return r;
}

__global__ __launch_bounds__(512) void preprocess_kernel(
    const float* __restrict__ in0, const float* __restrict__ in1,
    const float* __restrict__ in2, const float* __restrict__ in3,
    unsigned char* __restrict__ nT8, float* __restrict__ out) {
  // grid: x = 64 (k-strips of 64 rows = one kb block), y = 4 (mod).
  int mod = blockIdx.y;
  int k0 = blockIdx.x * 64;
  const float* X = sel_mod(mod, in0, in1, in2, in3) + (size_t)k0 * DDIM;

  if (blockIdx.x == 0 && blockIdx.y == 0 && threadIdx.x == 0)
    out[0] = 0.f;  // d_out re-poisoned each call; gram (next dispatch) accums

  __shared__ float rsc[64];
  // fp8-packed transpose tile: [512 cols][16 row-groups + 1 pad] words.
  // stride 17 (odd): pack-writes ~8 banks, out-phase b32 reads ~2-way (free).
  __shared__ unsigned int t8[512 * 17];  // 34.8 KB

  int t = threadIdx.x;
  int a = t >> 5;   // row-group 0..15 -> rows 4a..4a+3
  int bg = t & 31;  // col-group: float4 bg within each 128-col panel

  // single global read: 4 rows x 4 panels of float4 -> 64 VGPRs
  float4 v[4][4];  // [q][p]
#pragma unroll
  for (int q = 0; q < 4; ++q)
#pragma unroll
    for (int p = 0; p < 4; ++p)
      v[q][p] = ((const float4*)(X + (size_t)(4 * a + q) * DDIM + p * 128))[bg];

  // row-norm partials from registers; rows of group a live in one 32-lane
  // half-wave (t = a*32 + bg) -> width-32 shfl reduce
  float ss[4];
#pragma unroll
  for (int q = 0; q < 4; ++q) {
    float acc = 0.f;
#pragma unroll
    for (int p = 0; p < 4; ++p) {
      float4 u = v[q][p];
      acc += u.x * u.x + u.y * u.y + u.z * u.z + u.w * u.w;
    }
    ss[q] = acc;
  }
#pragma unroll
  for (int off = 16; off > 0; off >>= 1)
#pragma unroll
    for (int q = 0; q < 4; ++q) ss[q] += __shfl_down(ss[q], off, 32);
  if (bg == 0) {
#pragma unroll
    for (int q = 0; q < 4; ++q)
      rsc[4 * a + q] = 16.0f / fmaxf(sqrtf(ss[q]), 1e-12f);  // x16 folded
  }
  __syncthreads();

  float sc[4];
#pragma unroll
  for (int q = 0; q < 4; ++q) sc[q] = rsc[4 * a + q];

  // scale -> bf16 round -> fp8 pack (4 k-rows per word), straight from regs
#pragma unroll
  for (int p = 0; p < 4; ++p)
#pragma unroll
    for (int j = 0; j < 4; ++j) {
      float f0 = bfr(((const float*)&v[0][p])[j] * sc[0]);
      float f1 = bfr(((const float*)&v[1][p])[j] * sc[1]);
      float f2 = bfr(((const float*)&v[2][p])[j] * sc[2]);
      float f3 = bfr(((const float*)&v[3][p])[j] * sc[3]);
      unsigned int pk = __builtin_amdgcn_cvt_pk_fp8_f32(f0, f1, 0, 0);
      pk = __builtin_amdgcn_cvt_pk_fp8_f32(f2, f3, pk, 1);  // k-order bytes
      t8[(p * 128 + bg * 4 + j) * 17 + a] = pk;
    }
  __syncthreads();

  // output: one contiguous 32 KB region per block (k-blocked layout):
  // flat byte off = c*64 + g*16 = idx*16
  size_t rbase = (size_t)(mod * 64 + blockIdx.x) * 32768;
#pragma unroll
  for (int it = 0; it < 4; ++it) {
    int idx = it * 512 + t;
    int col = idx >> 2;  // 0..511
    int g = idx & 3;     // 16-byte k-group within the 64-row strip
    uint4 o;
    o.x = t8[col * 17 + g * 4 + 0];
    o.y = t8[col * 17 + g * 4 + 1];
    o.z = t8[col * 17 + g * 4 + 2];
    o.w = t8[col * 17 + g * 4 + 3];
    *(uint4*)(nT8 + rbase + (size_t)idx * 16) = o;
  }
}

__device__ __forceinline__ void stage_q(
    const unsigned char* __restrict__ mbase, int cbase, int k0,
    lds_u8p dst, int lane, int rowoff) {
  // One wave stages a QUARTER chunk: 32 panel rows x 128B of K
  // (4 global_load_lds). k-blocked layout: 16B k-slot gc of col c sits at
  //   ((kb0 + (gc>>2))*512 + c)*64 + (gc&3)*16   (== k-offset gc*16).
  // 16B-chunk XOR swizzle on the GLOBAL side: LDS slot s of local row r
  // holds global k-slot s ^ ((r>>1)&7); LDS side is the wave-uniform base +
  // lane*16 required by global_load_lds. Formulas identical to the proven
  // 64-row stage, just split by rowoff.
  int rr = lane >> 3;  // row 0..7 within the 8-row staging group
  int s = lane & 7;    // 16B slot within the 128B k-run
  int kb0 = k0 >> 6;
#pragma unroll
  for (int c = 0; c < 4; ++c) {
    int row = rowoff + c * 8 + rr;  // absolute local panel row 0..63
    int gc = s ^ ((row >> 1) & 7);
    const unsigned char* g =
        mbase + ((size_t)(kb0 + (gc >> 2)) * 512 + cbase + row) * 64 +
        (gc & 3) * 16;
    __builtin_amdgcn_global_load_lds(
        (__attribute__((address_space(1))) void*)(void*)g,
        (__attribute__((address_space(3))) void*)(dst + c * 1024),
        16, 0, 0);
  }
}

__device__ __forceinline__ void compute_q(lds_cu8p lsb, floatx4 acc[2][2],
                                          int mh, int nh, int lm, int lq) {
  // Wave (mh,nh) computes its 32x32 quadrant: A rows 32mh+mi*16+lm,
  // B rows 32nh+ni*16+lm; 32 B of K per lane (two asm ds_read_b128 at
  // unswizzled slots lq*2, lq*2+1) feed ONE K=128 mfma_scale per (mi,ni).
  // Unit scales (E8M0 0x7F) => plain fp8 product. Any operand-layout
  // mismatch is a uniform row/col/K permutation applied identically to A
  // and B => Frobenius-invariant.
  intx8 A8[2], B8[2];
#pragma unroll
  for (int mi = 0; mi < 2; ++mi) {
    int row = 32 * mh + mi * 16 + lm;  // local A row 0..63
    int sw = (row >> 1) & 7;
    *(llx2*)&A8[mi] = ldsr16(lsb + row * 128 + ((lq * 2) ^ sw) * 16);
    *((llx2*)&A8[mi] + 1) =
        ldsr16(lsb + row * 128 + ((lq * 2 + 1) ^ sw) * 16);
  }
#pragma unroll
  for (int ni = 0; ni < 2; ++ni) {
    int row = 32 * nh + ni * 16 + lm;  // local B row 0..63
    int sw = (row >> 1) & 7;
    *(llx2*)&B8[ni] =
        ldsr16(lsb + 8192 + row * 128 + ((lq * 2) ^ sw) * 16);
    *((llx2*)&B8[ni] + 1) =
        ldsr16(lsb + 8192 + row * 128 + ((lq * 2 + 1) ^ sw) * 16);
  }
  // ds_read results are NOT scoreboarded: wait, then fence the scheduler so
  // the MFMAs cannot be hoisted above the wait (rule #18).
  asm volatile("s_waitcnt lgkmcnt(0)");
  __builtin_amdgcn_sched_barrier(0);
  __builtin_amdgcn_s_setprio(1);
#pragma unroll
  for (int mi = 0; mi < 2; ++mi)
#pragma unroll
    for (int ni = 0; ni < 2; ++ni)
      acc[mi][ni] = __builtin_amdgcn_mfma_scale_f32_16x16x128_f8f6f4(
          A8[mi], B8[ni], acc[mi][ni], 0, 0,  // cbsz=0 (fp8), blgp=0 (fp8)
          0, 0x7F, 0, 0x7F);                  // opselA, scaleA, opselB, scaleB
  __builtin_amdgcn_s_setprio(0);
}

__global__ __launch_bounds__(256) void gram_frob_kernel(
    const unsigned char* __restrict__ nT8, float* __restrict__ out) {
  // 336 blocks x 4 waves, PAIR-GROUPED: jobs enumerated group-major over
  // unordered strip pairs {ti,tj} (diag groups: 4 self + 3 cross = 7 jobs;
  // off-diag: 4 self(x2) + 3 cross x 2 orientations = 10 jobs). XCD swizzle
  // (bx&7)*42 + bx>>3 puts each group's jobs on one XCD => panels stay
  // L2-resident.
  __shared__ __align__(16) unsigned char ls[5][16384];  // 5-deep, 80 KB
  __shared__ float red[4];

  int bx = blockIdx.x;
  int job = (bx & 7) * 42 + (bx >> 3);

  // decode job -> (ti, tj, idx-within-group)
  int rem = job, ti = 7, tj = 7;
  for (int i = 0; i < 8; ++i) {
    int rowlen = 7 + 10 * (7 - i);
    if (rem < rowlen) {
      if (rem < 7) {
        ti = i; tj = i;
      } else {
        int r2 = rem - 7;
        ti = i; tj = i + 1 + r2 / 10;
        rem = r2 % 10;
      }
      break;
    }
    rem -= rowlen;
  }

  int pa_, pb_, a0, b0;
  float wgt;
  if (ti == tj) {
    if (rem < 4) { pa_ = pb_ = rem; wgt = (rem == 3) ? 3.f : 1.f; }
    else         { pa_ = 3; pb_ = rem - 4; wgt = -2.f; }
    a0 = ti * 64; b0 = ti * 64;
  } else {
    if (rem < 4) {
      pa_ = pb_ = rem; wgt = (rem == 3) ? 6.f : 2.f;  // off-diag self x2
      a0 = ti * 64; b0 = tj * 64;
    } else {
      int k = rem - 4;
      pa_ = 3; pb_ = k >> 1; wgt = -2.f;
      if (k & 1) { a0 = tj * 64; b0 = ti * 64; }
      else       { a0 = ti * 64; b0 = tj * 64; }
    }
  }

  const unsigned char* Abase = nT8 + (size_t)pa_ * 2097152;  // 2 MB per mod
  const unsigned char* Bbase = nT8 + (size_t)pb_ * 2097152;

  int t = threadIdx.x;
  int w = t >> 6;     // wave 0..3
  int lane = t & 63;
  int lm = lane & 15;
  int lq = lane >> 4;
  int mh = w >> 1;    // output quadrant (mh, nh)
  int nh = w & 1;
  // stage role: waves 0-1 stage A rows 0-31 / 32-63; waves 2-3 stage B.
  const unsigned char* mbase = (w < 2) ? Abase : Bbase;
  int cbase = (w < 2) ? a0 : b0;
  int rowoff = (w & 1) * 32;
  int dsoff = (w >= 2 ? 8192 : 0) + (w & 1) * 4096;

  floatx4 zero = {0.f, 0.f, 0.f, 0.f};
  floatx4 acc[2][2];
  acc[0][0] = zero; acc[0][1] = zero; acc[1][0] = zero; acc[1][1] = zero;

  // 32 chunks of K=128, 5 buffers, 4-deep prefetch. Per-wave counted vmcnt
  // (4 own loads per stage, 4 chunks in flight = 16): wait own<=12 => own
  // chunk-i loads landed; raw s_barrier (no drain) publishes all quarters.
  lds_u8p lbase = (lds_u8p)(void*)&ls[0][0];
  lds_u8p p0 = lbase + 0 * 16384 + dsoff;
  lds_u8p p1 = lbase + 1 * 16384 + dsoff;
  lds_u8p p2 = lbase + 2 * 16384 + dsoff;
  lds_u8p p3 = lbase + 3 * 16384 + dsoff;
  lds_u8p p4 = lbase + 4 * 16384 + dsoff;
  stage_q(mbase, cbase, 0, p0, lane, rowoff);
  stage_q(mbase, cbase, 128, p1, lane, rowoff);
  stage_q(mbase, cbase, 256, p2, lane, rowoff);
  stage_q(mbase, cbase, 384, p3, lane, rowoff);
  for (int i = 0; i < 28; ++i) {
    asm volatile("s_waitcnt vmcnt(12)");
    __builtin_amdgcn_sched_barrier(0);
    __builtin_amdgcn_s_barrier();
    stage_q(mbase, cbase, (i + 4) * 128, p4, lane, rowoff);
    compute_q((lds_cu8p)(p0 - dsoff), acc, mh, nh, lm, lq);
    lds_u8p tmp = p0; p0 = p1; p1 = p2; p2 = p3; p3 = p4; p4 = tmp;
  }
  asm volatile("s_waitcnt vmcnt(12)");
  __builtin_amdgcn_sched_barrier(0);
  __builtin_amdgcn_s_barrier();
  compute_q((lds_cu8p)(p0 - dsoff), acc, mh, nh, lm, lq);  // chunk 28
  asm volatile("s_waitcnt vmcnt(8)");
  __builtin_amdgcn_sched_barrier(0);
  __builtin_amdgcn_s_barrier();
  compute_q((lds_cu8p)(p1 - dsoff), acc, mh, nh, lm, lq);  // chunk 29
  asm volatile("s_waitcnt vmcnt(4)");
  __builtin_amdgcn_sched_barrier(0);
  __builtin_amdgcn_s_barrier();
  compute_q((lds_cu8p)(p2 - dsoff), acc, mh, nh, lm, lq);  // chunk 30
  asm volatile("s_waitcnt vmcnt(0)");
  __builtin_amdgcn_sched_barrier(0);
  __builtin_amdgcn_s_barrier();
  compute_q((lds_cu8p)(p3 - dsoff), acc, mh, nh, lm, lq);  // chunk 31

  // Local Frobenius: C/D layout is a bijection and the 4 quadrants partition
  // the 64x64 tile -> sum of squares is exact.
  float s = 0.f;
#pragma unroll
  for (int mi = 0; mi < 2; ++mi)
#pragma unroll
    for (int ni = 0; ni < 2; ++ni)
#pragma unroll
      for (int r = 0; r < 4; ++r) {
        float v = acc[mi][ni][r];
        s += v * v;
      }
#pragma unroll
  for (int off = 32; off > 0; off >>= 1) s += __shfl_down(s, off, 64);
  if (lane == 0) red[w] = s;
  __syncthreads();
  if (t == 0) {
    float tot = red[0] + red[1] + red[2] + red[3];
    atomicAdd(out, wgt * LOSS_SCALE * tot);  // 336 atomics total
  }
}

extern "C" void kernel_launch(void* const* d_in, const int* in_sizes, int n_in,
                              void* d_out, int out_size, void* d_ws, size_t ws_size,
                              hipStream_t stream) {
  const float* in_rgb   = (const float*)d_in[0];
  const float* in_depth = (const float*)d_in[1];
  const float* in_ir    = (const float*)d_in[2];
  const float* in_t     = (const float*)d_in[3];

  unsigned char* nT8 = (unsigned char*)d_ws;  // 8 MB fp8, k-blocked layout

  preprocess_kernel<<<dim3(64, 4), 512, 0, stream>>>(
      in_rgb, in_depth, in_ir, in_t, nT8, (float*)d_out);
  gram_frob_kernel<<<dim3(336), 256, 0, stream>>>(nT8, (float*)d_out);
}